// Round 12
// baseline (112.854 us; speedup 1.0000x reference)
//
#include <hip/hip_runtime.h>

// Problem: B=8, T_en=T_de=D=U=256.
// out = de + softmax_e( sum_u tanh(ae[b,e,u]+ad[b,t,u]) * nu[u] ) @ en
// tanh(x) = 1 - 2/(e^{2x}+1);  e^{2x} = Ea * sd with
//   Ea[b,e,u] = exp2(C*ae)  [stored BF16, packed 4/u-group],
//   sd[b,t,u] = exp2(C*ad)  [fp32, scalar-loaded], C = 2*log2(e).
// Softmax: mu = SUM(nu) - 2*acc, acc = sum_u nu/(E+1); SUM(nu) drops out.
// 4-way rcp combine: sum nu_i/A_i = (n01*p23 + n23*p01)/(p01*p23).
// R10 note: Ea ring deeper than 4 spills to scratch — keep 4-deep.
// R11/R12: attn is L2-BW-bound (512MB) -> Ea & en in bf16 halves bytes;
//   bf16 rel err 2^-9 -> absmax ~0.005 vs 0.0956 threshold.
// Harness: ~80us/iter fixed overhead (256MB ws poison = 40us fill).

#define C2LOG2E 2.8853900817779268f   // 2*log2(e)

__device__ __forceinline__ const float* uptr(const float* p) {
    unsigned long long v = (unsigned long long)p;
    unsigned lo = __builtin_amdgcn_readfirstlane((unsigned)v);
    unsigned hi = __builtin_amdgcn_readfirstlane((unsigned)(v >> 32));
    return (const float*)((((unsigned long long)hi) << 32) | lo);
}

__device__ __forceinline__ unsigned f2bf(float f) {   // fp32 -> bf16 (RNE)
    unsigned b = __float_as_uint(f);
    return (b + 0x7fffu + ((b >> 16) & 1u)) >> 16;
}
__device__ __forceinline__ float bf_lo(unsigned w) {
    return __uint_as_float(w << 16);
}
__device__ __forceinline__ float bf_hi(unsigned w) {
    return __uint_as_float(w & 0xffff0000u);
}

// ---------------------------------------------------------------------------
// Projection GEMMs + exp2 epilogue. grid 1024 x 256thr:
//   blk<512 : att_en_bf[b][ug][e] = uint2 of 4 bf16 Ea values (u=4ug..4ug+3)
//             + en_bf16[b][e][d] copy of en rows
//   blk>=512: att_de_exp[b][t][u] = exp2(C*(de@w_de)) fp32
// Block = 4 rows x 256 cols. Wave wv = k-quarter for ALL 4 rows (A via
// uniform s_load ptrs, w coalesced b128, 4-deep prefetch); LDS reduce.
// ---------------------------------------------------------------------------
__global__ __launch_bounds__(256, 4) void gemm2(
    const float* __restrict__ en, const float* __restrict__ de,
    const float* __restrict__ w_en, const float* __restrict__ w_de,
    uint2* __restrict__ att_en_bf, unsigned short* __restrict__ en_bf16,
    float* __restrict__ att_de_exp)
{
    __shared__ float part[4 * 4 * 256];   // 16KB [wave][row][col]; reused

    const int isDe = blockIdx.x >> 9;
    const int rb   = blockIdx.x & 511;
    const float* x = isDe ? de : en;
    const float* w = isDe ? w_de : w_en;

    const int tid  = threadIdx.x;
    const int lane = tid & 63;
    const int wv   = __builtin_amdgcn_readfirstlane(tid >> 6);
    const int r0   = rb * 4;
    const int c0   = lane << 2;
    const int k0   = wv << 6;

    const float* ar0 = uptr(x + (r0 + 0) * 256 + k0);
    const float* ar1 = uptr(x + (r0 + 1) * 256 + k0);
    const float* ar2 = uptr(x + (r0 + 2) * 256 + k0);
    const float* ar3 = uptr(x + (r0 + 3) * 256 + k0);
    const float* wk  = w + k0 * 256 + c0;

    float4 acc0{0,0,0,0}, acc1{0,0,0,0}, acc2{0,0,0,0}, acc3{0,0,0,0};

    float4 wb[4], wn[4];
    #pragma unroll
    for (int j = 0; j < 4; ++j)
        wb[j] = *(const float4*)(wk + j * 256);

    for (int kk = 0; kk < 64; kk += 4) {
        if (kk < 60) {
            #pragma unroll
            for (int j = 0; j < 4; ++j)
                wn[j] = *(const float4*)(wk + (kk + 4 + j) * 256);
        }
        #pragma unroll
        for (int j = 0; j < 4; ++j) {
            const int k = kk + j;
            const float a0 = ar0[k], a1 = ar1[k];   // s_load
            const float a2 = ar2[k], a3 = ar3[k];
            acc0.x = fmaf(a0, wb[j].x, acc0.x); acc0.y = fmaf(a0, wb[j].y, acc0.y);
            acc0.z = fmaf(a0, wb[j].z, acc0.z); acc0.w = fmaf(a0, wb[j].w, acc0.w);
            acc1.x = fmaf(a1, wb[j].x, acc1.x); acc1.y = fmaf(a1, wb[j].y, acc1.y);
            acc1.z = fmaf(a1, wb[j].z, acc1.z); acc1.w = fmaf(a1, wb[j].w, acc1.w);
            acc2.x = fmaf(a2, wb[j].x, acc2.x); acc2.y = fmaf(a2, wb[j].y, acc2.y);
            acc2.z = fmaf(a2, wb[j].z, acc2.z); acc2.w = fmaf(a2, wb[j].w, acc2.w);
            acc3.x = fmaf(a3, wb[j].x, acc3.x); acc3.y = fmaf(a3, wb[j].y, acc3.y);
            acc3.z = fmaf(a3, wb[j].z, acc3.z); acc3.w = fmaf(a3, wb[j].w, acc3.w);
        }
        #pragma unroll
        for (int j = 0; j < 4; ++j) wb[j] = wn[j];
    }

    // write partials [wave][row][col]
    *(float4*)&part[(wv * 4 + 0) * 256 + c0] = acc0;
    *(float4*)&part[(wv * 4 + 1) * 256 + c0] = acc1;
    *(float4*)&part[(wv * 4 + 2) * 256 + c0] = acc2;
    *(float4*)&part[(wv * 4 + 3) * 256 + c0] = acc3;

    // en-path: emit bf16 copy of the 4 en rows (independent of LDS)
    if (!isDe) {
        #pragma unroll
        for (int j = 0; j < 4; ++j) {
            const float v = x[(r0 + j) * 256 + tid];   // coalesced
            en_bf16[(r0 + j) * 256 + tid] = (unsigned short)f2bf(v);
        }
    }
    __syncthreads();

    // reduce 4 k-partials; thread t = column u; scale + exp2
    const int t = tid;
    float s[4];
    #pragma unroll
    for (int j = 0; j < 4; ++j) {
        const float v = part[(0 * 4 + j) * 256 + t] + part[(1 * 4 + j) * 256 + t]
                      + part[(2 * 4 + j) * 256 + t] + part[(3 * 4 + j) * 256 + t];
        s[j] = __builtin_amdgcn_exp2f(v * C2LOG2E);
    }

    if (isDe) {
        const int rr0 = (rb * 4) & 2047;   // rows within (B*T_de)
        #pragma unroll
        for (int j = 0; j < 4; ++j)
            att_de_exp[(rr0 + j) * 256 + t] = s[j];
    } else {
        const int b  = rb >> 6;
        const int er = (rb & 63) * 4;
        __syncthreads();                    // all part reads done
        #pragma unroll
        for (int j = 0; j < 4; ++j)
            part[j * 256 + t] = s[j];       // [e_local][u]
        __syncthreads();
        // pack 4 u-values -> uint2 of bf16: att_en_bf[b][ug][er+el]
        const int ug = t >> 2;
        const int el = t & 3;
        const float* p4 = &part[el * 256 + (ug << 2)];
        const unsigned w0 = f2bf(p4[0]) | (f2bf(p4[1]) << 16);
        const unsigned w1 = f2bf(p4[2]) | (f2bf(p4[3]) << 16);
        att_en_bf[b * 16384 + ug * 256 + (er + el)] = uint2{w0, w1};
    }
}

// ---------------------------------------------------------------------------
// Attention. grid 1024 x 256thr, TT=2, b = blk&7 (XCD-affine).
// Stage 1: lane = e; uint2 loads = 4 bf16 Ea per e (4-deep ring, function
//   scope — deeper spills, see R10); sd/nu uniform s_loads; E=Ea*sd;
//   4-way rcp combine; no transcendentals in hot loop.
// Stage 2: waves 0,1 softmax (min-trick). Stage 3: thread=d, alphas uniform
//   b128 broadcasts, en read as coalesced bf16 (halved bytes).
// ---------------------------------------------------------------------------
__global__ __launch_bounds__(256, 4) void attn_kernel(
    const uint2* __restrict__ att_en_bf,         // (B,64,T_en): 4x bf16 Ea
    const unsigned short* __restrict__ en_bf16,  // (B,T_en,D) bf16
    const float* __restrict__ att_de_exp,        // (B,T_de,U): sd fp32
    const float* __restrict__ de_seq,            // (B,T_de,D)
    const float* __restrict__ nu,                // (U)
    float* __restrict__ out)                     // (B,T_de,D)
{
    const int blk  = blockIdx.x;          // 0..1023
    const int b    = blk & 7;
    const int t0   = (blk >> 3) << 1;
    const int tid  = threadIdx.x;
    const int lane = tid & 63;
    const int wv   = __builtin_amdgcn_readfirstlane(tid >> 6);

    __shared__ float s_mu[2][256];
    __shared__ float s_al[2][256];

    const uint2* aw  = att_en_bf + b * 16384 + (wv << 6) + lane;  // + ug*256
    const float* sd0 = uptr(att_de_exp + (b * 256 + t0) * 256);
    const float* sd1 = uptr(att_de_exp + (b * 256 + t0) * 256 + 256);
    const float* nuu = uptr(nu);

    // ---- Stage 1: acc[t] = sum_u nu[u] / (Ea*sd + 1) ----
    float acc0 = 0.f, acc1 = 0.f;
    uint2 cur[4], nxt[4];
    #pragma unroll
    for (int j = 0; j < 4; ++j)
        cur[j] = aw[j * 256];

    for (int ugb = 0; ugb < 64; ugb += 4) {
        if (ugb < 60) {
            #pragma unroll
            for (int j = 0; j < 4; ++j)
                nxt[j] = aw[(ugb + 4 + j) * 256];
        }
        #pragma unroll
        for (int j = 0; j < 4; ++j) {
            const int ub = (ugb + j) << 2;
            const float n0 = nuu[ub + 0], n1 = nuu[ub + 1];
            const float n2 = nuu[ub + 2], n3 = nuu[ub + 3];
            const float Ex = bf_lo(cur[j].x), Ey = bf_hi(cur[j].x);
            const float Ez = bf_lo(cur[j].y), Ew = bf_hi(cur[j].y);
            {   // t = t0
                const float A0 = fmaf(Ex, sd0[ub + 0], 1.f);
                const float A1 = fmaf(Ey, sd0[ub + 1], 1.f);
                const float A2 = fmaf(Ez, sd0[ub + 2], 1.f);
                const float A3 = fmaf(Ew, sd0[ub + 3], 1.f);
                const float p01 = A0 * A1, p23 = A2 * A3;
                const float n01 = fmaf(n0, A1, n1 * A0);
                const float n23 = fmaf(n2, A3, n3 * A2);
                const float num = fmaf(n01, p23, n23 * p01);
                acc0 = fmaf(num, __builtin_amdgcn_rcpf(p01 * p23), acc0);
            }
            {   // t = t0+1
                const float A0 = fmaf(Ex, sd1[ub + 0], 1.f);
                const float A1 = fmaf(Ey, sd1[ub + 1], 1.f);
                const float A2 = fmaf(Ez, sd1[ub + 2], 1.f);
                const float A3 = fmaf(Ew, sd1[ub + 3], 1.f);
                const float p01 = A0 * A1, p23 = A2 * A3;
                const float n01 = fmaf(n0, A1, n1 * A0);
                const float n23 = fmaf(n2, A3, n3 * A2);
                const float num = fmaf(n01, p23, n23 * p01);
                acc1 = fmaf(num, __builtin_amdgcn_rcpf(p01 * p23), acc1);
            }
        }
        #pragma unroll
        for (int j = 0; j < 4; ++j) cur[j] = nxt[j];
    }
    const int eidx = (wv << 6) + lane;
    s_mu[0][eidx] = acc0;
    s_mu[1][eidx] = acc1;
    __syncthreads();

    // ---- Stage 2: softmax for t = wv (logits = const - 2*acc) ----
    if (wv < 2) {
        const float4 a = *(const float4*)&s_mu[wv][lane << 2];
        float mn = fminf(fminf(a.x, a.y), fminf(a.z, a.w));
        #pragma unroll
        for (int off = 32; off > 0; off >>= 1)
            mn = fminf(mn, __shfl_xor(mn, off, 64));
        const float p0 = __builtin_amdgcn_exp2f((mn - a.x) * C2LOG2E);
        const float p1 = __builtin_amdgcn_exp2f((mn - a.y) * C2LOG2E);
        const float p2 = __builtin_amdgcn_exp2f((mn - a.z) * C2LOG2E);
        const float p3 = __builtin_amdgcn_exp2f((mn - a.w) * C2LOG2E);
        float ssum = (p0 + p1) + (p2 + p3);
        #pragma unroll
        for (int off = 32; off > 0; off >>= 1)
            ssum += __shfl_xor(ssum, off, 64);
        const float inv = __builtin_amdgcn_rcpf(ssum);
        float4 al; al.x = p0 * inv; al.y = p1 * inv;
        al.z = p2 * inv; al.w = p3 * inv;
        *(float4*)&s_al[wv][lane << 2] = al;
    }
    __syncthreads();

    // ---- Stage 3: out[t][d] = de[t][d] + sum_e alpha[t][e]*en[e][d] ----
    const unsigned short* en_b = en_bf16 + b * 65536 + tid;
    float o0 = 0.f, o1 = 0.f;
    for (int e0 = 0; e0 < 256; e0 += 8) {
        float v[8];
        #pragma unroll
        for (int j = 0; j < 8; ++j)
            v[j] = __uint_as_float(((unsigned)en_b[(e0 + j) << 8]) << 16);
        #pragma unroll
        for (int q = 0; q < 2; ++q) {
            const int eb = e0 + q * 4;
            const float4 A0 = *(const float4*)&s_al[0][eb];  // uniform bcast
            const float4 A1 = *(const float4*)&s_al[1][eb];
            o0 = fmaf(A0.x, v[q*4+0], o0); o1 = fmaf(A1.x, v[q*4+0], o1);
            o0 = fmaf(A0.y, v[q*4+1], o0); o1 = fmaf(A1.y, v[q*4+1], o1);
            o0 = fmaf(A0.z, v[q*4+2], o0); o1 = fmaf(A1.z, v[q*4+2], o1);
            o0 = fmaf(A0.w, v[q*4+3], o0); o1 = fmaf(A1.w, v[q*4+3], o1);
        }
    }
    const int base = (b * 256 + t0) * 256 + tid;
    out[base]       = de_seq[base]       + o0;
    out[base + 256] = de_seq[base + 256] + o1;
}

extern "C" void kernel_launch(void* const* d_in, const int* in_sizes, int n_in,
                              void* d_out, int out_size, void* d_ws, size_t ws_size,
                              hipStream_t stream) {
    const float* en_seq = (const float*)d_in[0];
    const float* de_seq = (const float*)d_in[1];
    const float* w_en   = (const float*)d_in[2];
    const float* w_de   = (const float*)d_in[3];
    const float* nu     = (const float*)d_in[4];
    float* out = (float*)d_out;

    char* ws = (char*)d_ws;
    uint2*          att_en_bf  = (uint2*)ws;                        // 1 MB
    unsigned short* en_bf16    = (unsigned short*)(ws + (1 << 20)); // 1 MB
    float*          att_de_exp = (float*)(ws + (2 << 20));          // 2 MB

    gemm2<<<1024, 256, 0, stream>>>(en_seq, de_seq, w_en, w_de,
                                    att_en_bf, en_bf16, att_de_exp);
    attn_kernel<<<1024, 256, 0, stream>>>(att_en_bf, en_bf16, att_de_exp,
                                          de_seq, nu, out);
}